// Round 3
// baseline (9649.859 us; speedup 1.0000x reference)
//
#include <hip/hip_runtime.h>
#include <cstddef>

#define NN 512
#define BSZ 128
#define TMAXN 1024
#define STEP_F 0.01f
#define EPS_F 1e-05f
#define MATSZ (NN*NN)        // 262144
#define MAT2 (2*MATSZ)
#define OUT_TN (TMAXN*NN)    // 524288
#define SKEW_SCALE 0.03125f  // 2^-5, 5 squarings
#define NBLOCKS 64

typedef __bf16 bf16x8 __attribute__((ext_vector_type(8)));
typedef float f32x4 __attribute__((ext_vector_type(4)));

// ---------------- small prep kernels ----------------

__global__ void prep_params(const float* __restrict__ A_raw,
                            const float* __restrict__ Theta_raw,
                            const float* __restrict__ Sigma_raw,
                            const float* __restrict__ bx_raw,
                            float* __restrict__ params,
                            float* __restrict__ theta,
                            float* __restrict__ sigma,
                            float* __restrict__ bx)
{
    int i = threadIdx.x;  // 512 threads
    if (i == 0) params[0] = fabsf(A_raw[0]) + EPS_F;
    theta[i] = fabsf(Theta_raw[i*NN + i]) + EPS_F;
    float sd = Sigma_raw[i*NN + i];
    sigma[i] = expf(-sd*sd);           // (1/G)*exp(-d^2), G=1
    bx[i] = bx_raw[i];
}

// S[z][i][j] = skew(raw_z)[i][j] * 2^-5
__global__ void build_S(const float* __restrict__ U_raw,
                        const float* __restrict__ V_raw,
                        float* __restrict__ S)
{
    int idx = blockIdx.x * 256 + threadIdx.x;   // 0 .. MAT2-1
    int z = idx >> 18;
    int rem = idx & (MATSZ - 1);
    int i = rem >> 9;
    int j = rem & (NN - 1);
    const float* src = (z == 0) ? U_raw : V_raw;
    float v = 0.0f;
    if (i < j)      v = src[i*NN + j];
    else if (i > j) v = -src[j*NN + i];
    S[idx] = v * SKEW_SCALE;
}

// ---------------- fp32 matmul: C = A*B (+C if accflag), batched over z ----------------
__global__ __launch_bounds__(256) void mm128(const float* __restrict__ A,
                                             const float* __restrict__ Bm,
                                             float* __restrict__ C,
                                             int accflag)
{
    int z = blockIdx.z;
    A  += (size_t)z * MATSZ;
    Bm += (size_t)z * MATSZ;
    C  += (size_t)z * MATSZ;

    __shared__ float As[8][128];   // [k][m]
    __shared__ float Bs[8][128];   // [k][n]

    int tid = threadIdx.x;
    int row0 = blockIdx.y * 128;
    int col0 = blockIdx.x * 128;
    int tx = tid & 15;
    int ty = tid >> 4;
    int arow = tid >> 1, akq = (tid & 1) * 4;
    int bkr  = tid >> 5, bcol = (tid & 31) * 4;

    float acc[8][8] = {{0.f}};

    for (int k0 = 0; k0 < NN; k0 += 8) {
        float4 av = *reinterpret_cast<const float4*>(&A[(size_t)(row0 + arow)*NN + k0 + akq]);
        float4 bv = *reinterpret_cast<const float4*>(&Bm[(size_t)(k0 + bkr)*NN + col0 + bcol]);
        As[akq+0][arow] = av.x; As[akq+1][arow] = av.y;
        As[akq+2][arow] = av.z; As[akq+3][arow] = av.w;
        *reinterpret_cast<float4*>(&Bs[bkr][bcol]) = bv;
        __syncthreads();
#pragma unroll
        for (int k = 0; k < 8; ++k) {
            float a[8], b[8];
            *reinterpret_cast<float4*>(&a[0]) = *reinterpret_cast<float4*>(&As[k][ty*8]);
            *reinterpret_cast<float4*>(&a[4]) = *reinterpret_cast<float4*>(&As[k][ty*8+4]);
            *reinterpret_cast<float4*>(&b[0]) = *reinterpret_cast<float4*>(&Bs[k][tx*8]);
            *reinterpret_cast<float4*>(&b[4]) = *reinterpret_cast<float4*>(&Bs[k][tx*8+4]);
#pragma unroll
            for (int i = 0; i < 8; ++i)
#pragma unroll
                for (int j = 0; j < 8; ++j)
                    acc[i][j] += a[i]*b[j];
        }
        __syncthreads();
    }

#pragma unroll
    for (int i = 0; i < 8; ++i) {
        size_t r = (size_t)(row0 + ty*8 + i);
        float* crow = &C[r*NN + col0 + tx*8];
        float4 v0 = {acc[i][0], acc[i][1], acc[i][2], acc[i][3]};
        float4 v1 = {acc[i][4], acc[i][5], acc[i][6], acc[i][7]};
        if (accflag) {
            float4 o0 = *reinterpret_cast<const float4*>(&crow[0]);
            float4 o1 = *reinterpret_cast<const float4*>(&crow[4]);
            v0.x += o0.x; v0.y += o0.y; v0.z += o0.z; v0.w += o0.w;
            v1.x += o1.x; v1.y += o1.y; v1.z += o1.z; v1.w += o1.w;
        }
        *reinterpret_cast<float4*>(&crow[0]) = v0;
        *reinterpret_cast<float4*>(&crow[4]) = v1;
    }
}

// Q0/Q1/Q2 for Paterson-Stockmeyer order-12 Taylor of exp
__global__ void combo3(const float* __restrict__ S, const float* __restrict__ S2,
                       const float* __restrict__ S3, const float* __restrict__ S4,
                       float* __restrict__ Q0, float* __restrict__ Q1,
                       float* __restrict__ Q2)
{
    const float C0 = 1.0f, C1 = 1.0f, C2 = 0.5f, C3 = 1.0f/6.0f;
    const float C4 = 1.0f/24.0f, C5 = 1.0f/120.0f, C6 = 1.0f/720.0f, C7 = 1.0f/5040.0f;
    const float C8 = 1.0f/40320.0f, C9 = 1.0f/362880.0f, C10 = 1.0f/3628800.0f;
    const float C11 = 1.0f/39916800.0f, C12 = 1.0f/479001600.0f;
    int idx = blockIdx.x * 256 + threadIdx.x;   // 0 .. MAT2-1
    int rem = idx & (MATSZ - 1);
    int i = rem >> 9;
    int j = rem & (NN - 1);
    float d = (i == j) ? 1.0f : 0.0f;
    float s = S[idx], s2 = S2[idx], s3 = S3[idx], s4 = S4[idx];
    Q0[idx] = C0*d + C1*s + C2*s2 + C3*s3;
    Q1[idx] = C4*d + C5*s + C6*s2 + C7*s3;
    Q2[idx] = C8*d + C9*s + C10*s2 + C11*s3 + C12*s4;
}

// Asc[i][j] = E_U[i][j]*sigma[j];  VT[i][j] = E_V[j][i]
__global__ void scale_transpose(const float* __restrict__ EU,
                                const float* __restrict__ EV,
                                const float* __restrict__ sigma,
                                float* __restrict__ Asc,
                                float* __restrict__ VT)
{
    int idx = blockIdx.x * 256 + threadIdx.x;   // 0..MATSZ-1
    int i = idx >> 9;
    int j = idx & (NN - 1);
    Asc[idx] = EU[idx] * sigma[j];
    VT[idx]  = EV[j*NN + i];
}

// Bh/Bl[r][k]: bf16 hi/lo split of B[r][k] = Bmm[r][k]*theta[k]/theta[r]
__global__ void finalize_Bsplit(const float* __restrict__ Bmm,
                                const float* __restrict__ theta,
                                __bf16* __restrict__ Bh,
                                __bf16* __restrict__ Bl)
{
    int idx = blockIdx.x * 256 + threadIdx.x;   // 0..MATSZ-1
    int r = idx >> 9;
    int k = idx & (NN - 1);
    float v = Bmm[idx] * theta[k] / theta[r];
    __bf16 h = (__bf16)v;
    Bh[idx] = h;
    Bl[idx] = (__bf16)(v - (float)h);
}

// xb0 = X0 (layout [b][n]); out[b, 0, n] = X0[b][n]
__global__ void init_x(const float* __restrict__ X0,
                       float* __restrict__ xb0,
                       float* __restrict__ out)
{
    int idx = blockIdx.x * 256 + threadIdx.x;   // 0..65535
    int b = idx >> 9;
    int n = idx & (NN - 1);
    float v = X0[idx];
    xb0[idx] = v;
    out[(size_t)b * OUT_TN + n] = v;
}

// ---------------- persistent step kernel (cooperative) ----------------
// 64 blocks x 256 threads (4 waves). Block: col-group cg=bid&7 (16 cols),
// row-group rg=bid>>3 (64 rows); wave w owns 16-row tile r0=(rg*4+w)*16.
// B (hi/lo) lives in VGPRs for the whole 1023-step loop.
__global__ __launch_bounds__(256) void step_persist(
    const float* __restrict__ x0buf,  // [128][512] state at t=0
    float* __restrict__ x1buf,
    const __bf16* __restrict__ Bh,    // [512][512] row-major [r][k]
    const __bf16* __restrict__ Bl,
    const float* __restrict__ params,
    const float* __restrict__ bx,
    float* __restrict__ out,
    unsigned* cnt, unsigned* gen)
{
    __shared__ bf16x8 xsv[2048];      // 32 KB: hi [0,16K), lo [16K,32K)
    char* xs = (char*)xsv;
    int tid = threadIdx.x;
    int bid = blockIdx.x;
    int cg = bid & 7;
    int rg = bid >> 3;
    int w = tid >> 6;
    int l = tid & 63;

    // ---- preload A-fragments (B rows) into registers ----
    int r0 = (rg*4 + w) * 16;
    int arow = l & 15;
    int kch  = l >> 4;
    bf16x8 ah[16], al[16];
    {
        const __bf16* bhrow = Bh + (size_t)(r0 + arow)*NN + kch*8;
        const __bf16* blrow = Bl + (size_t)(r0 + arow)*NN + kch*8;
#pragma unroll
        for (int ks = 0; ks < 16; ++ks) {
            ah[ks] = *reinterpret_cast<const bf16x8*>(bhrow + ks*32);
            al[ks] = *reinterpret_cast<const bf16x8*>(blrow + ks*32);
        }
    }

    int c_l  = l & 15;
    int crow = r0 + (l >> 4)*4;
    int ccol = cg*16 + c_l;
    float c0 = 1.0f - STEP_F * (params[0]);
    float4 bv = *reinterpret_cast<const float4*>(&bx[crow]);
    int xbase = c_l * 1024;
    int xsw   = (c_l & 7) << 4;

    // staging indices
    int sc  = tid & 15;                // col 0..15
    int skb = (tid >> 4) << 5;         // k base 0..480 step 32
    int scb = sc * 1024;
    int ssw = (sc & 7) << 4;

    const float* xcur = x0buf;
    float* xnxt = x1buf;

    for (int t = 1; t < TMAXN; ++t) {
        // ---- stage relu(x) hi/lo into LDS ----
        {
            const float* src = xcur + (size_t)(cg*16 + sc)*NN + skb;
#pragma unroll
            for (int q = 0; q < 4; ++q) {
                float4 f0 = *reinterpret_cast<const float4*>(src + q*8);
                float4 f1 = *reinterpret_cast<const float4*>(src + q*8 + 4);
                float v[8] = {f0.x, f0.y, f0.z, f0.w, f1.x, f1.y, f1.z, f1.w};
                bf16x8 h, lo;
#pragma unroll
                for (int e = 0; e < 8; ++e) {
                    float x = fmaxf(v[e], 0.0f);
                    __bf16 hh = (__bf16)x;
                    h[e] = hh;
                    lo[e] = (__bf16)(x - (float)hh);
                }
                int koff = (skb + q*8) * 2;
                int ad = scb + (koff ^ ssw);
                *reinterpret_cast<bf16x8*>(&xs[ad]) = h;
                *reinterpret_cast<bf16x8*>(&xs[16384 + ad]) = lo;
            }
        }
        __syncthreads();

        // ---- MFMA: acc = B * relu(x) with hi/lo compensation ----
        f32x4 acc0 = {0,0,0,0}, acc1 = {0,0,0,0}, acc2 = {0,0,0,0};
#pragma unroll
        for (int ks = 0; ks < 16; ++ks) {
            int koff = (ks*32 + kch*8) * 2;
            int ad = xbase + (koff ^ xsw);
            bf16x8 xh = *reinterpret_cast<const bf16x8*>(&xs[ad]);
            bf16x8 xl = *reinterpret_cast<const bf16x8*>(&xs[16384 + ad]);
            acc0 = __builtin_amdgcn_mfma_f32_16x16x32_bf16(ah[ks], xh, acc0, 0, 0, 0);
            acc1 = __builtin_amdgcn_mfma_f32_16x16x32_bf16(al[ks], xh, acc1, 0, 0, 0);
            acc2 = __builtin_amdgcn_mfma_f32_16x16x32_bf16(ah[ks], xl, acc2, 0, 0, 0);
        }

        // ---- epilogue: Euler update + trajectory write ----
        float4 xo = *reinterpret_cast<const float4*>(&xcur[(size_t)ccol*NN + crow]);
        float4 nv;
        nv.x = c0*xo.x + STEP_F*(acc0[0] + acc1[0] + acc2[0] + bv.x);
        nv.y = c0*xo.y + STEP_F*(acc0[1] + acc1[1] + acc2[1] + bv.y);
        nv.z = c0*xo.z + STEP_F*(acc0[2] + acc1[2] + acc2[2] + bv.z);
        nv.w = c0*xo.w + STEP_F*(acc0[3] + acc1[3] + acc2[3] + bv.w);
        *reinterpret_cast<float4*>(&xnxt[(size_t)ccol*NN + crow]) = nv;
        *reinterpret_cast<float4*>(&out[(size_t)ccol*OUT_TN + (size_t)t*NN + crow]) = nv;

        // ---- device-wide barrier (monotonic generation) ----
        __syncthreads();               // all waves' stores issued (vmcnt drained)
        if (tid == 0) {
            __threadfence();           // release: flush this XCD's L2 to coherence point
            unsigned prev = __hip_atomic_fetch_add(cnt, 1u, __ATOMIC_ACQ_REL,
                                                   __HIP_MEMORY_SCOPE_AGENT);
            if (prev == (unsigned)NBLOCKS * (unsigned)t - 1u) {
                __hip_atomic_store(gen, (unsigned)t, __ATOMIC_RELEASE,
                                   __HIP_MEMORY_SCOPE_AGENT);
            } else {
                while (__hip_atomic_load(gen, __ATOMIC_RELAXED,
                                         __HIP_MEMORY_SCOPE_AGENT) < (unsigned)t) {
                    __builtin_amdgcn_s_sleep(1);
                }
            }
            __threadfence();           // acquire: invalidate stale L1/L2
        }
        __syncthreads();

        const float* tmp = xcur; xcur = xnxt; xnxt = (float*)tmp;
    }
}

// ---------------- host ----------------

extern "C" void kernel_launch(void* const* d_in, const int* in_sizes, int n_in,
                              void* d_out, int out_size, void* d_ws, size_t ws_size,
                              hipStream_t stream)
{
    const float* X0        = (const float*)d_in[0];
    const float* A_raw     = (const float*)d_in[1];
    const float* Theta_raw = (const float*)d_in[2];
    const float* U_raw     = (const float*)d_in[3];
    const float* Sigma_raw = (const float*)d_in[4];
    const float* V_raw     = (const float*)d_in[5];
    const float* bx_raw    = (const float*)d_in[6];
    float* out = (float*)d_out;

    // expm scratch lives in d_out (256 MB; fully overwritten by the steps after)
    float* S   = out;               // [2][512][512]
    float* S2  = out + 1*MAT2;
    float* S3  = out + 2*MAT2;
    float* S4  = out + 3*MAT2;
    float* Q2b = out + 4*MAT2;
    float* Q1b = out + 5*MAT2;
    float* Q0b = out + 6*MAT2;      // 7*MAT2*4B = 14.7 MB << 256 MB

    // persistent storage in d_ws
    char* wsc = (char*)d_ws;
    __bf16* Bh = (__bf16*)wsc;                        // 512 KB
    __bf16* Bl = (__bf16*)(wsc + 524288);             // 512 KB
    float* xb0 = (float*)(wsc + 1048576);             // 256 KB
    float* xb1 = (float*)(wsc + 1048576 + 262144);    // 256 KB
    float* params = (float*)(wsc + 1048576 + 2*262144);
    float* theta  = params + 64;
    float* sigma  = theta + 512;
    float* bx     = sigma + 512;
    unsigned* barrier_mem = (unsigned*)(wsc + 2*1048576);  // cnt @ +0, gen @ +32

    prep_params<<<1, 512, 0, stream>>>(A_raw, Theta_raw, Sigma_raw, bx_raw,
                                       params, theta, sigma, bx);
    build_S<<<MAT2/256, 256, 0, stream>>>(U_raw, V_raw, S);

    // Paterson-Stockmeyer order-12 Taylor: P = Q0 + S4*(Q1 + S4*Q2)
    mm128<<<dim3(4,4,2), 256, 0, stream>>>(S,  S,   S2,  0);   // S2 = S*S
    mm128<<<dim3(4,4,2), 256, 0, stream>>>(S2, S,   S3,  0);   // S3 = S2*S
    mm128<<<dim3(4,4,2), 256, 0, stream>>>(S2, S2,  S4,  0);   // S4 = S2*S2
    combo3<<<MAT2/256, 256, 0, stream>>>(S, S2, S3, S4, Q0b, Q1b, Q2b);
    mm128<<<dim3(4,4,2), 256, 0, stream>>>(S4, Q2b, Q1b, 1);   // R = Q1 + S4*Q2
    mm128<<<dim3(4,4,2), 256, 0, stream>>>(S4, Q1b, Q0b, 1);   // P = Q0 + S4*R
    // 5 squarings
    float* Pa = Q0b; float* Pb = Q2b;
    for (int q = 0; q < 5; ++q) {
        mm128<<<dim3(4,4,2), 256, 0, stream>>>(Pa, Pa, Pb, 0);
        float* t2 = Pa; Pa = Pb; Pb = t2;
    }
    // Pa = [E_U ; E_V]

    scale_transpose<<<MATSZ/256, 256, 0, stream>>>(Pa, Pa + MATSZ, sigma,
                                                   S, S + MATSZ);     // Asc, VT
    mm128<<<dim3(4,4,1), 256, 0, stream>>>(S, S + MATSZ, S2, 0);      // Bmm = Asc*VT
    finalize_Bsplit<<<MATSZ/256, 256, 0, stream>>>(S2, theta, Bh, Bl);

    init_x<<<BSZ*NN/256, 256, 0, stream>>>(X0, xb0, out);

    hipMemsetAsync(barrier_mem, 0, 256, stream);

    unsigned* cnt = barrier_mem;
    unsigned* gen = barrier_mem + 8;
    void* args[] = { (void*)&xb0, (void*)&xb1, (void*)&Bh, (void*)&Bl,
                     (void*)&params, (void*)&bx, (void*)&out,
                     (void*)&cnt, (void*)&gen };
    hipLaunchCooperativeKernel((const void*)step_persist, dim3(NBLOCKS), dim3(256),
                               args, 0, stream);
}

// Round 4
// 5520.150 us; speedup vs baseline: 1.7481x; 1.7481x over previous
//
#include <hip/hip_runtime.h>
#include <cstddef>

#define NN 512
#define BSZ 128
#define TMAXN 1024
#define STEP_F 0.01f
#define EPS_F 1e-05f
#define MATSZ (NN*NN)        // 262144
#define MAT2 (2*MATSZ)
#define OUT_TN (TMAXN*NN)    // 524288
#define SKEW_SCALE 0.03125f  // 2^-5, 5 squarings
#define NBLOCKS 32           // 8 cg x 4 rg

typedef __bf16 bf16x8 __attribute__((ext_vector_type(8)));
typedef float f32x4 __attribute__((ext_vector_type(4)));

// ---------------- small prep kernels ----------------

__global__ void prep_params(const float* __restrict__ A_raw,
                            const float* __restrict__ Theta_raw,
                            const float* __restrict__ Sigma_raw,
                            const float* __restrict__ bx_raw,
                            float* __restrict__ params,
                            float* __restrict__ theta,
                            float* __restrict__ sigma,
                            float* __restrict__ bx)
{
    int i = threadIdx.x;  // 512 threads
    if (i == 0) params[0] = fabsf(A_raw[0]) + EPS_F;
    theta[i] = fabsf(Theta_raw[i*NN + i]) + EPS_F;
    float sd = Sigma_raw[i*NN + i];
    sigma[i] = expf(-sd*sd);           // (1/G)*exp(-d^2), G=1
    bx[i] = bx_raw[i];
}

// S[z][i][j] = skew(raw_z)[i][j] * 2^-5
__global__ void build_S(const float* __restrict__ U_raw,
                        const float* __restrict__ V_raw,
                        float* __restrict__ S)
{
    int idx = blockIdx.x * 256 + threadIdx.x;   // 0 .. MAT2-1
    int z = idx >> 18;
    int rem = idx & (MATSZ - 1);
    int i = rem >> 9;
    int j = rem & (NN - 1);
    const float* src = (z == 0) ? U_raw : V_raw;
    float v = 0.0f;
    if (i < j)      v = src[i*NN + j];
    else if (i > j) v = -src[j*NN + i];
    S[idx] = v * SKEW_SCALE;
}

// ---------------- fp32 matmul: C = A*B (+C if accflag), batched over z ----------------
__global__ __launch_bounds__(256) void mm128(const float* __restrict__ A,
                                             const float* __restrict__ Bm,
                                             float* __restrict__ C,
                                             int accflag)
{
    int z = blockIdx.z;
    A  += (size_t)z * MATSZ;
    Bm += (size_t)z * MATSZ;
    C  += (size_t)z * MATSZ;

    __shared__ float As[8][128];   // [k][m]
    __shared__ float Bs[8][128];   // [k][n]

    int tid = threadIdx.x;
    int row0 = blockIdx.y * 128;
    int col0 = blockIdx.x * 128;
    int tx = tid & 15;
    int ty = tid >> 4;
    int arow = tid >> 1, akq = (tid & 1) * 4;
    int bkr  = tid >> 5, bcol = (tid & 31) * 4;

    float acc[8][8] = {{0.f}};

    for (int k0 = 0; k0 < NN; k0 += 8) {
        float4 av = *reinterpret_cast<const float4*>(&A[(size_t)(row0 + arow)*NN + k0 + akq]);
        float4 bv = *reinterpret_cast<const float4*>(&Bm[(size_t)(k0 + bkr)*NN + col0 + bcol]);
        As[akq+0][arow] = av.x; As[akq+1][arow] = av.y;
        As[akq+2][arow] = av.z; As[akq+3][arow] = av.w;
        *reinterpret_cast<float4*>(&Bs[bkr][bcol]) = bv;
        __syncthreads();
#pragma unroll
        for (int k = 0; k < 8; ++k) {
            float a[8], b[8];
            *reinterpret_cast<float4*>(&a[0]) = *reinterpret_cast<float4*>(&As[k][ty*8]);
            *reinterpret_cast<float4*>(&a[4]) = *reinterpret_cast<float4*>(&As[k][ty*8+4]);
            *reinterpret_cast<float4*>(&b[0]) = *reinterpret_cast<float4*>(&Bs[k][tx*8]);
            *reinterpret_cast<float4*>(&b[4]) = *reinterpret_cast<float4*>(&Bs[k][tx*8+4]);
#pragma unroll
            for (int i = 0; i < 8; ++i)
#pragma unroll
                for (int j = 0; j < 8; ++j)
                    acc[i][j] += a[i]*b[j];
        }
        __syncthreads();
    }

#pragma unroll
    for (int i = 0; i < 8; ++i) {
        size_t r = (size_t)(row0 + ty*8 + i);
        float* crow = &C[r*NN + col0 + tx*8];
        float4 v0 = {acc[i][0], acc[i][1], acc[i][2], acc[i][3]};
        float4 v1 = {acc[i][4], acc[i][5], acc[i][6], acc[i][7]};
        if (accflag) {
            float4 o0 = *reinterpret_cast<const float4*>(&crow[0]);
            float4 o1 = *reinterpret_cast<const float4*>(&crow[4]);
            v0.x += o0.x; v0.y += o0.y; v0.z += o0.z; v0.w += o0.w;
            v1.x += o1.x; v1.y += o1.y; v1.z += o1.z; v1.w += o1.w;
        }
        *reinterpret_cast<float4*>(&crow[0]) = v0;
        *reinterpret_cast<float4*>(&crow[4]) = v1;
    }
}

// Q0/Q1/Q2 for Paterson-Stockmeyer order-12 Taylor of exp
__global__ void combo3(const float* __restrict__ S, const float* __restrict__ S2,
                       const float* __restrict__ S3, const float* __restrict__ S4,
                       float* __restrict__ Q0, float* __restrict__ Q1,
                       float* __restrict__ Q2)
{
    const float C0 = 1.0f, C1 = 1.0f, C2 = 0.5f, C3 = 1.0f/6.0f;
    const float C4 = 1.0f/24.0f, C5 = 1.0f/120.0f, C6 = 1.0f/720.0f, C7 = 1.0f/5040.0f;
    const float C8 = 1.0f/40320.0f, C9 = 1.0f/362880.0f, C10 = 1.0f/3628800.0f;
    const float C11 = 1.0f/39916800.0f, C12 = 1.0f/479001600.0f;
    int idx = blockIdx.x * 256 + threadIdx.x;   // 0 .. MAT2-1
    int rem = idx & (MATSZ - 1);
    int i = rem >> 9;
    int j = rem & (NN - 1);
    float d = (i == j) ? 1.0f : 0.0f;
    float s = S[idx], s2 = S2[idx], s3 = S3[idx], s4 = S4[idx];
    Q0[idx] = C0*d + C1*s + C2*s2 + C3*s3;
    Q1[idx] = C4*d + C5*s + C6*s2 + C7*s3;
    Q2[idx] = C8*d + C9*s + C10*s2 + C11*s3 + C12*s4;
}

// Asc[i][j] = E_U[i][j]*sigma[j];  VT[i][j] = E_V[j][i]
__global__ void scale_transpose(const float* __restrict__ EU,
                                const float* __restrict__ EV,
                                const float* __restrict__ sigma,
                                float* __restrict__ Asc,
                                float* __restrict__ VT)
{
    int idx = blockIdx.x * 256 + threadIdx.x;   // 0..MATSZ-1
    int i = idx >> 9;
    int j = idx & (NN - 1);
    Asc[idx] = EU[idx] * sigma[j];
    VT[idx]  = EV[j*NN + i];
}

// Bh/Bl[r][k]: bf16 hi/lo split of B[r][k] = Bmm[r][k]*theta[k]/theta[r]
__global__ void finalize_Bsplit(const float* __restrict__ Bmm,
                                const float* __restrict__ theta,
                                __bf16* __restrict__ Bh,
                                __bf16* __restrict__ Bl)
{
    int idx = blockIdx.x * 256 + threadIdx.x;   // 0..MATSZ-1
    int r = idx >> 9;
    int k = idx & (NN - 1);
    float v = Bmm[idx] * theta[k] / theta[r];
    __bf16 h = (__bf16)v;
    Bh[idx] = h;
    Bl[idx] = (__bf16)(v - (float)h);
}

// xb0 = X0 (layout [b][n]); out[b, 0, n] = X0[b][n]
__global__ void init_x(const float* __restrict__ X0,
                       float* __restrict__ xb0,
                       float* __restrict__ out)
{
    int idx = blockIdx.x * 256 + threadIdx.x;   // 0..65535
    int b = idx >> 9;
    int n = idx & (NN - 1);
    float v = X0[idx];
    xb0[idx] = v;
    out[(size_t)b * OUT_TN + n] = v;
}

// ---------------- persistent step kernel (cooperative) ----------------
// 32 blocks x 512 threads (8 waves). cg = bid&7 (16 batch cols), rg = bid>>3
// (128 rows). Wave w owns rows rg*128 + w*16. B (hi/lo) pinned in VGPRs.
// x ping-pong exchanged ONLY via relaxed agent-scope atomics (L2-bypass) --
// no __threadfence in the loop, so B stays cache/register resident.
// Sync domain = the 4 blocks sharing cg (independent per cg).
__global__ __launch_bounds__(512, 2) void step_persist(
    const float* __restrict__ x0buf,  // [128][512] state at t=0
    float* __restrict__ x1buf,
    const __bf16* __restrict__ Bh,    // [512][512] row-major [r][k]
    const __bf16* __restrict__ Bl,
    const float* __restrict__ params,
    const float* __restrict__ bx,
    float* __restrict__ out,
    unsigned* __restrict__ barrier_mem)   // per cg: cnt @ cg*64, gen @ cg*64+16 (dwords)
{
    __shared__ char xs[32768];        // hi [0,16K), lo [16K,32K); [c][k] swizzled
    int tid = threadIdx.x;
    int bid = blockIdx.x;
    int cg = bid & 7;
    int rg = bid >> 3;
    int w = tid >> 6;
    int l = tid & 63;

    // ---- preload A-fragments (B rows) into registers, pinned for the loop ----
    int r0 = rg*128 + w*16;
    int arow = l & 15;
    int kch  = l >> 4;
    bf16x8 ah[16], al[16];
    {
        const __bf16* bhrow = Bh + (size_t)(r0 + arow)*NN + kch*8;
        const __bf16* blrow = Bl + (size_t)(r0 + arow)*NN + kch*8;
#pragma unroll
        for (int ks = 0; ks < 16; ++ks) {
            ah[ks] = *reinterpret_cast<const bf16x8*>(bhrow + ks*32);
            al[ks] = *reinterpret_cast<const bf16x8*>(blrow + ks*32);
        }
    }

    int c_l  = l & 15;
    int crow = r0 + (l >> 4)*4;
    int ccol = cg*16 + c_l;
    float c0 = 1.0f - STEP_F * (params[0]);
    float4 bv = *reinterpret_cast<const float4*>(&bx[crow]);
    int xbase = c_l * 1024;
    int xsw   = (c_l & 7) << 4;

    // staging mapping: thread (sc = tid>>5, ks = tid&31) loads k = 32*i + ks
    // -> per load-instr, consecutive lanes read consecutive dwords (coalesced)
    int sc = tid >> 5;                 // col 0..15
    int ks_l = tid & 31;
    int scb = sc * 1024;
    int ssw = (sc & 7) << 4;

    unsigned* cnt = barrier_mem + (size_t)cg * 64;
    unsigned* gen = cnt + 16;

    const float* xcur = x0buf;
    float* xnxt = x1buf;

    for (int t = 1; t < TMAXN; ++t) {
        // ---- stage relu(x) hi/lo into LDS (cache-bypass loads) ----
        {
            float* src = (float*)(xcur + (size_t)(cg*16 + sc)*NN);
            float v[16];
#pragma unroll
            for (int i = 0; i < 16; ++i)
                v[i] = __hip_atomic_load(&src[i*32 + ks_l], __ATOMIC_RELAXED,
                                         __HIP_MEMORY_SCOPE_AGENT);
#pragma unroll
            for (int i = 0; i < 16; ++i) {
                float x = fmaxf(v[i], 0.0f);
                __bf16 hh = (__bf16)x;
                __bf16 ll = (__bf16)(x - (float)hh);
                int k = i*32 + ks_l;
                int ad = scb + ((2*k) ^ ssw);
                *reinterpret_cast<__bf16*>(&xs[ad]) = hh;
                *reinterpret_cast<__bf16*>(&xs[16384 + ad]) = ll;
            }
        }
        __syncthreads();

        // ---- MFMA: acc = B * relu(x) with hi/lo compensation ----
        f32x4 acc0 = {0,0,0,0}, acc1 = {0,0,0,0}, acc2 = {0,0,0,0};
#pragma unroll
        for (int ks = 0; ks < 16; ++ks) {
            int koff = (ks*32 + kch*8) * 2;
            int ad = xbase + (koff ^ xsw);
            bf16x8 xh = *reinterpret_cast<const bf16x8*>(&xs[ad]);
            bf16x8 xl = *reinterpret_cast<const bf16x8*>(&xs[16384 + ad]);
            acc0 = __builtin_amdgcn_mfma_f32_16x16x32_bf16(ah[ks], xh, acc0, 0, 0, 0);
            acc1 = __builtin_amdgcn_mfma_f32_16x16x32_bf16(al[ks], xh, acc1, 0, 0, 0);
            acc2 = __builtin_amdgcn_mfma_f32_16x16x32_bf16(ah[ks], xl, acc2, 0, 0, 0);
        }

        // ---- epilogue: Euler update + writes ----
        float* xc = (float*)(xcur + (size_t)ccol*NN + crow);
        float xo0 = __hip_atomic_load(&xc[0], __ATOMIC_RELAXED, __HIP_MEMORY_SCOPE_AGENT);
        float xo1 = __hip_atomic_load(&xc[1], __ATOMIC_RELAXED, __HIP_MEMORY_SCOPE_AGENT);
        float xo2 = __hip_atomic_load(&xc[2], __ATOMIC_RELAXED, __HIP_MEMORY_SCOPE_AGENT);
        float xo3 = __hip_atomic_load(&xc[3], __ATOMIC_RELAXED, __HIP_MEMORY_SCOPE_AGENT);
        float4 nv;
        nv.x = c0*xo0 + STEP_F*(acc0[0] + acc1[0] + acc2[0] + bv.x);
        nv.y = c0*xo1 + STEP_F*(acc0[1] + acc1[1] + acc2[1] + bv.y);
        nv.z = c0*xo2 + STEP_F*(acc0[2] + acc1[2] + acc2[2] + bv.z);
        nv.w = c0*xo3 + STEP_F*(acc0[3] + acc1[3] + acc2[3] + bv.w);
        float* xn = xnxt + (size_t)ccol*NN + crow;
        __hip_atomic_store(&xn[0], nv.x, __ATOMIC_RELAXED, __HIP_MEMORY_SCOPE_AGENT);
        __hip_atomic_store(&xn[1], nv.y, __ATOMIC_RELAXED, __HIP_MEMORY_SCOPE_AGENT);
        __hip_atomic_store(&xn[2], nv.z, __ATOMIC_RELAXED, __HIP_MEMORY_SCOPE_AGENT);
        __hip_atomic_store(&xn[3], nv.w, __ATOMIC_RELAXED, __HIP_MEMORY_SCOPE_AGENT);
        *reinterpret_cast<float4*>(&out[(size_t)ccol*OUT_TN + (size_t)t*NN + crow]) = nv;

        // ---- cg-domain barrier (4 blocks, monotonic generation) ----
        if (t < TMAXN - 1) {
            __syncthreads();           // drains vmcnt: all atomic stores acked
            if (tid == 0) {
                unsigned prev = __hip_atomic_fetch_add(cnt, 1u, __ATOMIC_RELAXED,
                                                       __HIP_MEMORY_SCOPE_AGENT);
                if (prev == 4u*(unsigned)t - 1u) {
                    __hip_atomic_store(gen, (unsigned)t, __ATOMIC_RELAXED,
                                       __HIP_MEMORY_SCOPE_AGENT);
                } else {
                    while (__hip_atomic_load(gen, __ATOMIC_RELAXED,
                                             __HIP_MEMORY_SCOPE_AGENT) < (unsigned)t) {
                        __builtin_amdgcn_s_sleep(1);
                    }
                }
            }
            __syncthreads();
            asm volatile("" ::: "memory");   // compiler fence: no load hoisting
        }

        const float* tmp = xcur; xcur = xnxt; xnxt = (float*)tmp;
    }
}

// ---------------- host ----------------

extern "C" void kernel_launch(void* const* d_in, const int* in_sizes, int n_in,
                              void* d_out, int out_size, void* d_ws, size_t ws_size,
                              hipStream_t stream)
{
    const float* X0        = (const float*)d_in[0];
    const float* A_raw     = (const float*)d_in[1];
    const float* Theta_raw = (const float*)d_in[2];
    const float* U_raw     = (const float*)d_in[3];
    const float* Sigma_raw = (const float*)d_in[4];
    const float* V_raw     = (const float*)d_in[5];
    const float* bx_raw    = (const float*)d_in[6];
    float* out = (float*)d_out;

    // expm scratch lives in d_out (256 MB; fully overwritten by the steps after)
    float* S   = out;               // [2][512][512]
    float* S2  = out + 1*MAT2;
    float* S3  = out + 2*MAT2;
    float* S4  = out + 3*MAT2;
    float* Q2b = out + 4*MAT2;
    float* Q1b = out + 5*MAT2;
    float* Q0b = out + 6*MAT2;      // 7*MAT2*4B = 14.7 MB << 256 MB

    // persistent storage in d_ws
    char* wsc = (char*)d_ws;
    __bf16* Bh = (__bf16*)wsc;                        // 512 KB
    __bf16* Bl = (__bf16*)(wsc + 524288);             // 512 KB
    float* xb0 = (float*)(wsc + 1048576);             // 256 KB
    float* xb1 = (float*)(wsc + 1048576 + 262144);    // 256 KB
    float* params = (float*)(wsc + 1048576 + 2*262144);
    float* theta  = params + 64;
    float* sigma  = theta + 512;
    float* bx     = sigma + 512;
    unsigned* barrier_mem = (unsigned*)(wsc + 2*1048576);  // 8 cg * 256 B

    prep_params<<<1, 512, 0, stream>>>(A_raw, Theta_raw, Sigma_raw, bx_raw,
                                       params, theta, sigma, bx);
    build_S<<<MAT2/256, 256, 0, stream>>>(U_raw, V_raw, S);

    // Paterson-Stockmeyer order-12 Taylor: P = Q0 + S4*(Q1 + S4*Q2)
    mm128<<<dim3(4,4,2), 256, 0, stream>>>(S,  S,   S2,  0);   // S2 = S*S
    mm128<<<dim3(4,4,2), 256, 0, stream>>>(S2, S,   S3,  0);   // S3 = S2*S
    mm128<<<dim3(4,4,2), 256, 0, stream>>>(S2, S2,  S4,  0);   // S4 = S2*S2
    combo3<<<MAT2/256, 256, 0, stream>>>(S, S2, S3, S4, Q0b, Q1b, Q2b);
    mm128<<<dim3(4,4,2), 256, 0, stream>>>(S4, Q2b, Q1b, 1);   // R = Q1 + S4*Q2
    mm128<<<dim3(4,4,2), 256, 0, stream>>>(S4, Q1b, Q0b, 1);   // P = Q0 + S4*R
    // 5 squarings
    float* Pa = Q0b; float* Pb = Q2b;
    for (int q = 0; q < 5; ++q) {
        mm128<<<dim3(4,4,2), 256, 0, stream>>>(Pa, Pa, Pb, 0);
        float* t2 = Pa; Pa = Pb; Pb = t2;
    }
    // Pa = [E_U ; E_V]

    scale_transpose<<<MATSZ/256, 256, 0, stream>>>(Pa, Pa + MATSZ, sigma,
                                                   S, S + MATSZ);     // Asc, VT
    mm128<<<dim3(4,4,1), 256, 0, stream>>>(S, S + MATSZ, S2, 0);      // Bmm = Asc*VT
    finalize_Bsplit<<<MATSZ/256, 256, 0, stream>>>(S2, theta, Bh, Bl);

    init_x<<<BSZ*NN/256, 256, 0, stream>>>(X0, xb0, out);

    hipMemsetAsync(barrier_mem, 0, 2048, stream);

    void* args[] = { (void*)&xb0, (void*)&xb1, (void*)&Bh, (void*)&Bl,
                     (void*)&params, (void*)&bx, (void*)&out,
                     (void*)&barrier_mem };
    hipLaunchCooperativeKernel((const void*)step_persist, dim3(NBLOCKS), dim3(512),
                               args, 0, stream);
}